// Round 10
// baseline (152.825 us; speedup 1.0000x reference)
//
#include <hip/hip_runtime.h>
#include <cmath>

#define T_LEN 262144
#define NROW 8
#define NL 30
#define NT 512
#define PPT 3                        /* f32x2 pairs per thread per tile */
#define EXT (NT * PPT * 2)           /* 3072 positions per tile */
#define HALO 576
#define TILE (EXT - HALO)            /* 2496 */
#define PB 106                       /* tiles per row = ceil(262144/2496) */
#define JB (PB / 2)                  /* 53 block-cols per row (2 tiles/block) */
#define PAD 32
#define CH 2048                      /* elements per scale chunk */
#define RB (T_LEN / CH)              /* 128 chunks per row */
#define NB2 (NROW * RB)              /* 1024 */

#define NEG2LOG2E -2.885390082f      /* -2*log2(e) */
#define NEGLOG2E  -1.4426950409f     /* -log2(e)  */

#if __has_builtin(__builtin_amdgcn_exp2f)
#define EXP2(x) __builtin_amdgcn_exp2f(x)
#else
#define EXP2(x) __expf(0.6931471805599453f * (x))
#endif

typedef float f32x2 __attribute__((ext_vector_type(2)));

__device__ __forceinline__ float fast_rcp(float x) { return __builtin_amdgcn_rcpf(x); }

__device__ __forceinline__ f32x2 exp2v(f32x2 x) {
    f32x2 r; r.x = EXP2(x.x); r.y = EXP2(x.y); return r;
}
__device__ __forceinline__ f32x2 rcpv(f32x2 x) {
    f32x2 r; r.x = fast_rcp(x.x); r.y = fast_rcp(x.y); return r;
}

// One gated layer over BOTH tiles, then one barrier (if WB).
// D even; CUT = progressive dead-halo bound (compile-time).
template<int D, int CUT, bool WB>
__device__ __forceinline__ void layer2(
    int k,
    const float* __restrict__ fw, const float* __restrict__ fb,
    const float* __restrict__ gw, const float* __restrict__ gb,
    const float* __restrict__ rw, const float* __restrict__ rb,
    const float* __restrict__ s0, float* __restrict__ d0,
    const float* __restrict__ s1, float* __restrict__ d1,
    f32x2 (&h0)[PPT], f32x2 (&sk0)[PPT],
    f32x2 (&h1)[PPT], f32x2 (&sk1)[PPT], int tid)
{
    const float f0 = fw[k*5+0], f1 = fw[k*5+1], f2 = fw[k*5+2], f3 = fw[k*5+3], f4 = fw[k*5+4];
    const float fbk = fb[k];
    const float g0 = gw[k*5+0], g1 = gw[k*5+1], g2 = gw[k*5+2], g3 = gw[k*5+3], g4 = gw[k*5+4];
    const float gbk = gb[k];
    const float rwk = rw[k], rbk = rb[k];

    auto body = [&](const float* __restrict__ src, float* __restrict__ dst,
                    f32x2 (&h)[PPT], f32x2 (&skip)[PPT]) {
        #pragma unroll
        for (int p = 0; p < PPT; ++p) {
            const int i2 = 2 * (tid + p * NT);
            if (2 * p * NT < CUT) {              // only pair 0 can be dead
                if ((i2 + 1) < CUT) continue;
            }
            const f32x2 v0 = *(const f32x2*)&src[i2 - 4*D];
            const f32x2 v1 = *(const f32x2*)&src[i2 - 3*D];
            const f32x2 v2 = *(const f32x2*)&src[i2 - 2*D];
            const f32x2 v3 = *(const f32x2*)&src[i2 -   D];
            const f32x2 v4 = h[p];

            f32x2 af = fbk + f0 * v0;
            af = f1 * v1 + af;
            af = f2 * v2 + af;
            af = f3 * v3 + af;
            af = f4 * v4 + af;
            f32x2 ag = gbk + g0 * v0;
            ag = g1 * v1 + ag;
            ag = g2 * v2 + ag;
            ag = g3 * v3 + ag;
            ag = g4 * v4 + ag;

            // z = tanh(af)*sigmoid(ag) = (1-u)/((1+u)(1+w))
            const f32x2 u = exp2v(af * NEG2LOG2E);
            const f32x2 w = exp2v(ag * NEGLOG2E);
            const f32x2 num = 1.0f - u;
            const f32x2 den = (1.0f + u) * (1.0f + w);
            const f32x2 z = num * rcpv(den);
            skip[p] += z;
            if (WB) {
                h[p] = (z * rwk + rbk) + v4;
                *(f32x2*)&dst[i2] = h[p];
            }
        }
    };
    body(s0, d0, h0, sk0);
    body(s1, d1, h1, sk1);
    if (WB) __syncthreads();
}

// d=1 gated layer (layer 0) over both tiles + one barrier.
__device__ __forceinline__ void layer2_d1(
    const float* __restrict__ fw, const float* __restrict__ fb,
    const float* __restrict__ gw, const float* __restrict__ gb,
    const float* __restrict__ rw, const float* __restrict__ rb,
    const float* __restrict__ s0, float* __restrict__ d0,
    const float* __restrict__ s1, float* __restrict__ d1,
    f32x2 (&h0)[PPT], f32x2 (&sk0)[PPT],
    f32x2 (&h1)[PPT], f32x2 (&sk1)[PPT], int tid)
{
    const float f0 = fw[0], f1 = fw[1], f2 = fw[2], f3 = fw[3], f4 = fw[4];
    const float fbk = fb[0];
    const float g0 = gw[0], g1 = gw[1], g2 = gw[2], g3 = gw[3], g4 = gw[4];
    const float gbk = gb[0];
    const float rwk = rw[0], rbk = rb[0];

    auto body = [&](const float* __restrict__ src, float* __restrict__ dst,
                    f32x2 (&h)[PPT], f32x2 (&skip)[PPT]) {
        #pragma unroll
        for (int p = 0; p < PPT; ++p) {
            const int i2 = 2 * (tid + p * NT);
            const f32x2 a = *(const f32x2*)&src[i2 - 4];
            const f32x2 b = *(const f32x2*)&src[i2 - 2];
            const f32x2 c = h[p];
            f32x2 v0, v1, v2, v3;
            v0.x = a.x; v0.y = a.y;
            v1.x = a.y; v1.y = b.x;
            v2.x = b.x; v2.y = b.y;
            v3.x = b.y; v3.y = c.x;

            f32x2 af = fbk + f0 * v0;
            af = f1 * v1 + af;
            af = f2 * v2 + af;
            af = f3 * v3 + af;
            af = f4 * c  + af;
            f32x2 ag = gbk + g0 * v0;
            ag = g1 * v1 + ag;
            ag = g2 * v2 + ag;
            ag = g3 * v3 + ag;
            ag = g4 * c  + ag;

            const f32x2 u = exp2v(af * NEG2LOG2E);
            const f32x2 w = exp2v(ag * NEGLOG2E);
            const f32x2 num = 1.0f - u;
            const f32x2 den = (1.0f + u) * (1.0f + w);
            const f32x2 z = num * rcpv(den);
            skip[p] += z;
            h[p] = (z * rwk + rbk) + c;
            *(f32x2*)&dst[i2] = h[p];
        }
    };
    body(s0, d0, h0, sk0);
    body(s1, d1, h1, sk1);
    __syncthreads();
}

// ---------------------------------------------------------------------------
__global__ __launch_bounds__(NT, 4)
void k_wavenet(const float* __restrict__ x,
               const float* __restrict__ cw,  const float* __restrict__ cb,
               const float* __restrict__ fw,  const float* __restrict__ fb,
               const float* __restrict__ gw,  const float* __restrict__ gb,
               const float* __restrict__ rw,  const float* __restrict__ rb,
               const float* __restrict__ c1w, const float* __restrict__ c1b,
               const float* __restrict__ c2w, const float* __restrict__ c2b,
               float* __restrict__ eout, float* __restrict__ partsum)
{
    __shared__ __align__(16) float rA0[PAD + EXT];
    __shared__ __align__(16) float rB0[PAD + EXT];
    __shared__ __align__(16) float rA1[PAD + EXT];
    __shared__ __align__(16) float rB1[PAD + EXT];
    __shared__ float reds[NT / 64];
    float* A0 = rA0 + PAD;  float* B0 = rB0 + PAD;
    float* A1 = rA1 + PAD;  float* B1 = rB1 + PAD;

    const int tid = threadIdx.x;
    const int row = blockIdx.x / JB;
    const int jj  = blockIdx.x % JB;
    const int t0a = (2 * jj)     * TILE;
    const int t0b = (2 * jj + 1) * TILE;

    if (tid < PAD) { rA0[tid] = 0.0f; rB0[tid] = 0.0f; rA1[tid] = 0.0f; rB1[tid] = 0.0f; }

    const float* xr = x + (size_t)row * T_LEN;
    f32x2 h0[PPT], sk0[PPT], h1[PPT], sk1[PPT];

    // stage both tiles into A-buffers
    {
        auto stage = [&](int t0, float* buf, f32x2 (&h)[PPT], f32x2 (&skip)[PPT]) {
            #pragma unroll
            for (int p = 0; p < PPT; ++p) {
                const int i2 = 2 * (tid + p * NT);
                const int g = t0 - HALO + i2;
                f32x2 v;
                v.x = (g     >= 0 && g     < T_LEN) ? xr[g]     : 0.0f;
                v.y = (g + 1 >= 0 && g + 1 < T_LEN) ? xr[g + 1] : 0.0f;
                *(f32x2*)&buf[i2] = v;
                h[p] = v;
                skip[p].x = 0.0f; skip[p].y = 0.0f;
            }
        };
        stage(t0a, A0, h0, sk0);
        stage(t0b, A1, h1, sk1);
        __syncthreads();
    }

    // initial causal conv (d=1): A -> B, both tiles
    {
        const float w0 = cw[0], w1 = cw[1], w2 = cw[2], w3 = cw[3], w4 = cw[4];
        const float b  = cb[0];
        auto iconv = [&](const float* src, float* dst, f32x2 (&h)[PPT]) {
            #pragma unroll
            for (int p = 0; p < PPT; ++p) {
                const int i2 = 2 * (tid + p * NT);
                const f32x2 a  = *(const f32x2*)&src[i2 - 4];
                const f32x2 bb = *(const f32x2*)&src[i2 - 2];
                const f32x2 c  = h[p];
                f32x2 v0, v1, v2, v3;
                v0.x = a.x;  v0.y = a.y;
                v1.x = a.y;  v1.y = bb.x;
                v2.x = bb.x; v2.y = bb.y;
                v3.x = bb.y; v3.y = c.x;
                f32x2 acc = b + w0 * v0;
                acc = w1 * v1 + acc;
                acc = w2 * v2 + acc;
                acc = w3 * v3 + acc;
                acc = w4 * c  + acc;
                h[p] = acc;
                *(f32x2*)&dst[i2] = acc;
            }
        };
        iconv(A0, B0, h0);
        iconv(A1, B1, h1);
        __syncthreads();
    }

    // 30 layers, fully unrolled; ping-pong B->A->B...; one barrier per layer.
    layer2_d1(fw, fb, gw, gb, rw, rb, B0, A0, B1, A1, h0, sk0, h1, sk1, tid);
    layer2<2,  16, true >( 1, fw, fb, gw, gb, rw, rb, A0, B0, A1, B1, h0, sk0, h1, sk1, tid);
    layer2<4,  32, true >( 2, fw, fb, gw, gb, rw, rb, B0, A0, B1, A1, h0, sk0, h1, sk1, tid);
    layer2<8,  64, true >( 3, fw, fb, gw, gb, rw, rb, A0, B0, A1, B1, h0, sk0, h1, sk1, tid);
    layer2<6,  88, true >( 4, fw, fb, gw, gb, rw, rb, B0, A0, B1, A1, h0, sk0, h1, sk1, tid);
    layer2<2,  96, true >( 5, fw, fb, gw, gb, rw, rb, A0, B0, A1, B1, h0, sk0, h1, sk1, tid);
    layer2<4, 112, true >( 6, fw, fb, gw, gb, rw, rb, B0, A0, B1, A1, h0, sk0, h1, sk1, tid);
    layer2<8, 144, true >( 7, fw, fb, gw, gb, rw, rb, A0, B0, A1, B1, h0, sk0, h1, sk1, tid);
    layer2<6, 168, true >( 8, fw, fb, gw, gb, rw, rb, B0, A0, B1, A1, h0, sk0, h1, sk1, tid);
    layer2<2, 176, true >( 9, fw, fb, gw, gb, rw, rb, A0, B0, A1, B1, h0, sk0, h1, sk1, tid);
    layer2<4, 192, true >(10, fw, fb, gw, gb, rw, rb, B0, A0, B1, A1, h0, sk0, h1, sk1, tid);
    layer2<8, 224, true >(11, fw, fb, gw, gb, rw, rb, A0, B0, A1, B1, h0, sk0, h1, sk1, tid);
    layer2<6, 248, true >(12, fw, fb, gw, gb, rw, rb, B0, A0, B1, A1, h0, sk0, h1, sk1, tid);
    layer2<2, 256, true >(13, fw, fb, gw, gb, rw, rb, A0, B0, A1, B1, h0, sk0, h1, sk1, tid);
    layer2<4, 272, true >(14, fw, fb, gw, gb, rw, rb, B0, A0, B1, A1, h0, sk0, h1, sk1, tid);
    layer2<8, 304, true >(15, fw, fb, gw, gb, rw, rb, A0, B0, A1, B1, h0, sk0, h1, sk1, tid);
    layer2<6, 328, true >(16, fw, fb, gw, gb, rw, rb, B0, A0, B1, A1, h0, sk0, h1, sk1, tid);
    layer2<2, 336, true >(17, fw, fb, gw, gb, rw, rb, A0, B0, A1, B1, h0, sk0, h1, sk1, tid);
    layer2<4, 352, true >(18, fw, fb, gw, gb, rw, rb, B0, A0, B1, A1, h0, sk0, h1, sk1, tid);
    layer2<8, 384, true >(19, fw, fb, gw, gb, rw, rb, A0, B0, A1, B1, h0, sk0, h1, sk1, tid);
    layer2<6, 408, true >(20, fw, fb, gw, gb, rw, rb, B0, A0, B1, A1, h0, sk0, h1, sk1, tid);
    layer2<2, 416, true >(21, fw, fb, gw, gb, rw, rb, A0, B0, A1, B1, h0, sk0, h1, sk1, tid);
    layer2<4, 432, true >(22, fw, fb, gw, gb, rw, rb, B0, A0, B1, A1, h0, sk0, h1, sk1, tid);
    layer2<8, 464, true >(23, fw, fb, gw, gb, rw, rb, A0, B0, A1, B1, h0, sk0, h1, sk1, tid);
    layer2<6, 488, true >(24, fw, fb, gw, gb, rw, rb, B0, A0, B1, A1, h0, sk0, h1, sk1, tid);
    layer2<2, 496, true >(25, fw, fb, gw, gb, rw, rb, A0, B0, A1, B1, h0, sk0, h1, sk1, tid);
    layer2<4, 512, true >(26, fw, fb, gw, gb, rw, rb, B0, A0, B1, A1, h0, sk0, h1, sk1, tid);
    layer2<8, 544, true >(27, fw, fb, gw, gb, rw, rb, A0, B0, A1, B1, h0, sk0, h1, sk1, tid);
    layer2<6, 568, true >(28, fw, fb, gw, gb, rw, rb, B0, A0, B1, A1, h0, sk0, h1, sk1, tid);
    layer2<2, 576, false>(29, fw, fb, gw, gb, rw, rb, A0, B0, A1, B1, h0, sk0, h1, sk1, tid);

    // epilogue: 1x1 convs + mu-law expand; write e = exp(v); partial sum
    const float w1 = c1w[0], b1 = c1b[0], w2 = c2w[0], b2 = c2b[0];
    float s = 0.0f;
    float* er = eout + (size_t)row * T_LEN;
    auto epi = [&](int t0, f32x2 (&skip)[PPT]) {
        #pragma unroll
        for (int p = 0; p < PPT; ++p) {
            const int i2 = 2 * (tid + p * NT);
            if (i2 >= HALO) {
                const int t = t0 + i2 - HALO;
                if (t < T_LEN) {
                    f32x2 sk = skip[p];
                    float ox = fmaf(fmaxf(sk.x, 0.0f), w1, b1);
                    float oy = fmaf(fmaxf(sk.y, 0.0f), w1, b1);
                    ox = fmaf(fmaxf(ox, 0.0f), w2, b2);
                    oy = fmaf(fmaxf(oy, 0.0f), w2, b2);
                    float vx = fmaf(EXP2(8.0f * fabsf(ox)), (1.0f/255.0f), -(1.0f/255.0f));
                    float vy = fmaf(EXP2(8.0f * fabsf(oy)), (1.0f/255.0f), -(1.0f/255.0f));
                    vx = copysignf(vx, ox);
                    vy = copysignf(vy, oy);
                    const float ex = __expf(vx);
                    const float ey = __expf(vy);
                    f32x2 e; e.x = ex; e.y = ey;
                    *(f32x2*)&er[t] = e;
                    s += ex + ey;
                }
            }
        }
    };
    epi(t0a, sk0);
    epi(t0b, sk1);

    #pragma unroll
    for (int off = 32; off >= 1; off >>= 1) s += __shfl_xor(s, off, 64);
    if ((tid & 63) == 0) reds[tid >> 6] = s;
    __syncthreads();
    if (tid == 0) {
        float ss = 0.0f;
        #pragma unroll
        for (int w = 0; w < NT / 64; ++w) ss += reds[w];
        partsum[blockIdx.x] = ss;
    }
}

// ---------------------------------------------------------------------------
__global__ __launch_bounds__(256)
void k_scale(float* __restrict__ ebuf, const float* __restrict__ partsum)
{
    const int tid = threadIdx.x;
    const int row = blockIdx.x / RB;

    __shared__ float red[4];
    float s = (tid < JB) ? partsum[row * JB + tid] : 0.0f;
    #pragma unroll
    for (int off = 32; off >= 1; off >>= 1) s += __shfl_xor(s, off, 64);
    if ((tid & 63) == 0) red[tid >> 6] = s;
    __syncthreads();
    const float tot = (red[0] + red[1]) + (red[2] + red[3]);
    const float inv = 1.0f / tot;

    float4* vp = (float4*)(ebuf + (size_t)blockIdx.x * CH);
    #pragma unroll
    for (int q = 0; q < 2; ++q) {
        float4 v = vp[tid + q * 256];
        v.x *= inv; v.y *= inv; v.z *= inv; v.w *= inv;
        vp[tid + q * 256] = v;
    }
}

// ---------------------------------------------------------------------------
extern "C" void kernel_launch(void* const* d_in, const int* in_sizes, int n_in,
                              void* d_out, int out_size, void* d_ws, size_t ws_size,
                              hipStream_t stream)
{
    const float* x   = (const float*)d_in[0];
    const float* cw  = (const float*)d_in[1];
    const float* cb  = (const float*)d_in[2];
    const float* fw  = (const float*)d_in[3];
    const float* fb  = (const float*)d_in[4];
    const float* gw  = (const float*)d_in[5];
    const float* gb  = (const float*)d_in[6];
    const float* rw  = (const float*)d_in[7];
    const float* rb  = (const float*)d_in[8];
    const float* c1w = (const float*)d_in[9];
    const float* c1b = (const float*)d_in[10];
    const float* c2w = (const float*)d_in[11];
    const float* c2b = (const float*)d_in[12];

    float* eout    = (float*)d_out;
    float* partsum = (float*)d_ws;            // NROW*JB = 424 floats

    k_wavenet<<<NROW * JB, NT, 0, stream>>>(x, cw, cb, fw, fb, gw, gb, rw, rb,
                                            c1w, c1b, c2w, c2b, eout, partsum);
    k_scale<<<NB2, 256, 0, stream>>>(eout, partsum);
}